// Round 7
// baseline (191.362 us; speedup 1.0000x reference)
//
#include <hip/hip_runtime.h>
#include <hip/hip_bf16.h>

// Problem constants
#define BB 16384
#define LL 9
#define DD 32
#define CR 128

typedef float v2 __attribute__((ext_vector_type(2)));

// --- guaranteed VOP3P packed-fp32 ops (compiler wasn't emitting them) ---
// pk_fma_lo: d = {s.lo, s.lo} * a + c   (broadcast low half of s)
__device__ __forceinline__ v2 pk_fma_lo(v2 s, v2 a, v2 c) {
    v2 d;
    asm("v_pk_fma_f32 %0, %1, %2, %3 op_sel:[0,0,0] op_sel_hi:[0,1,1]"
        : "=v"(d) : "v"(s), "v"(a), "v"(c));
    return d;
}
// pk_fma_hi: d = {s.hi, s.hi} * a + c   (broadcast high half of s)
__device__ __forceinline__ v2 pk_fma_hi(v2 s, v2 a, v2 c) {
    v2 d;
    asm("v_pk_fma_f32 %0, %1, %2, %3 op_sel:[1,0,0] op_sel_hi:[1,1,1]"
        : "=v"(d) : "v"(s), "v"(a), "v"(c));
    return d;
}
__device__ __forceinline__ v2 pk_add(v2 a, v2 b) {
    v2 d;
    asm("v_pk_add_f32 %0, %1, %2" : "=v"(d) : "v"(a), "v"(b));
    return d;
}

// ws layout (floats): A1[32][128], A2[32][128], WK[17][128]
// A1 = Wi@W1, A2 = Wj@W1, WK[k] = (relpos_row_k@Wr + br + bi + bj)@W1 + b1

__global__ void precomp_kernel(const float* __restrict__ relpos,
                               const float* __restrict__ Wi, const float* __restrict__ bi,
                               const float* __restrict__ Wj, const float* __restrict__ bj,
                               const float* __restrict__ Wr, const float* __restrict__ br,
                               const float* __restrict__ W1, const float* __restrict__ b1,
                               float* __restrict__ ws)
{
    __shared__ float rv[DD];
    float* A1 = ws;
    float* A2 = ws + DD * CR;
    float* WK = ws + 2 * DD * CR;

    const int c = threadIdx.x;   // 0..127
    const int blk = blockIdx.x;  // 0..80

    if (blk < 32) {
        const int d = blk;
        float s = 0.f;
        #pragma unroll
        for (int e = 0; e < DD; ++e) s = fmaf(Wi[d * DD + e], W1[e * CR + c], s);
        A1[d * CR + c] = s;
    } else if (blk < 64) {
        const int d = blk - 32;
        float s = 0.f;
        #pragma unroll
        for (int e = 0; e < DD; ++e) s = fmaf(Wj[d * DD + e], W1[e * CR + c], s);
        A2[d * CR + c] = s;
    } else {
        const int k = blk - 64;       // 0..16, dk = k-8 = i-j
        const int dk = k - 8;
        const int i = dk > 0 ? dk : 0;
        const int j = i - dk;
        if (c < DD) {
            float s = bi[c] + bj[c] + br[c];
            #pragma unroll
            for (int d = 0; d < DD; ++d)
                s = fmaf(relpos[(i * LL + j) * DD + d], Wr[d * DD + c], s);
            rv[c] = s;
        }
        __syncthreads();
        float s = b1[c];
        #pragma unroll
        for (int e = 0; e < DD; ++e) s = fmaf(rv[e], W1[e * CR + c], s);
        WK[k * CR + c] = s;
    }
}

// 4 batches per wave IN FLIGHT (ILP, not occupancy): U/V[4][9] v2 live (144 regs),
// tables streamed from L1 (8.6 KB, hot), packed-fp32 asm ops, 256-VGPR budget.
__global__ __launch_bounds__(256, 2)
void outersum_main(const float* __restrict__ seq,
                   const float* __restrict__ ws,
                   const float* __restrict__ W2,
                   const float* __restrict__ b2,
                   float* __restrict__ out)
{
    const float* gA1 = ws;
    const float* gA2 = ws + DD * CR;
    const float* gWK = ws + 2 * DD * CR;

    const int lane = threadIdx.x & 63;
    const int wid  = blockIdx.x * 4 + (threadIdx.x >> 6);   // 0..4095
    const int cp = lane * 2;            // channels (cp, cp+1) per lane

    // wk pairs + W2 rows: small, keep in regs.
    v2 wk[17];
    #pragma unroll
    for (int k = 0; k < 17; ++k) wk[k] = *(const v2*)(gWK + k * CR + cp);
    const float4 w4 = *(const float4*)(W2 + 2 * cp);  // {W2[c0][0],W2[c0][1],W2[c1][0],W2[c1][1]}
    const float bias0 = 81.f * b2[0], bias1 = 81.f * b2[1];

    // Launder group offset into a VGPR -> guaranteed vector loads for seq.
    int soff = wid * (4 * LL * DD);
    asm volatile("" : "+v"(soff));
    const float* sbase = seq + soff;

    v2 U[4][LL], V[4][LL];
    #pragma unroll
    for (int p = 0; p < 4; ++p)
        #pragma unroll
        for (int i = 0; i < LL; ++i) { U[p][i] = (v2)0.f; V[p][i] = (v2)0.f; }

    // ---- GEMV: dc-outer (runtime loop, small code), 4-batch interleave ----
    #pragma unroll 1
    for (int dc = 0; dc < 8; ++dc) {
        v2 a1s[4], a2s[4];
        #pragma unroll
        for (int t = 0; t < 4; ++t) {
            a1s[t] = *(const v2*)(gA1 + (dc * 4 + t) * CR + cp);   // L1-hot
            a2s[t] = *(const v2*)(gA2 + (dc * 4 + t) * CR + cp);
        }
        const float* sd = sbase + dc * 4;
        #pragma unroll
        for (int p = 0; p < 4; ++p) {
            #pragma unroll
            for (int i = 0; i < LL; ++i) {
                const float4 s = *(const float4*)(sd + (p * LL + i) * DD);
                v2 s01; s01.x = s.x; s01.y = s.y;
                v2 s23; s23.x = s.z; s23.y = s.w;
                U[p][i] = pk_fma_lo(s01, a1s[0], U[p][i]);
                U[p][i] = pk_fma_hi(s01, a1s[1], U[p][i]);
                U[p][i] = pk_fma_lo(s23, a1s[2], U[p][i]);
                U[p][i] = pk_fma_hi(s23, a1s[3], U[p][i]);
                V[p][i] = pk_fma_lo(s01, a2s[0], V[p][i]);
                V[p][i] = pk_fma_hi(s01, a2s[1], V[p][i]);
                V[p][i] = pk_fma_lo(s23, a2s[2], V[p][i]);
                V[p][i] = pk_fma_hi(s23, a2s[3], V[p][i]);
            }
        }
    }

    // ---- Outer: q[c] = sum_ij relu(U+V+wk); W2 folded once at the end ----
    v2 q[4];
    #pragma unroll
    for (int p = 0; p < 4; ++p) q[p] = (v2)0.f;
    #pragma unroll
    for (int i = 0; i < LL; ++i) {
        #pragma unroll
        for (int j = 0; j < LL; ++j) {
            const v2 w = wk[i - j + 8];
            #pragma unroll
            for (int p = 0; p < 4; ++p) {
                v2 t = pk_add(U[p][i], V[p][j]);
                t = pk_add(t, w);
                t.x = fmaxf(t.x, 0.f);          // no v_pk_max_f32 on CDNA: 2x v_max_f32
                t.y = fmaxf(t.y, 0.f);
                q[p] = pk_add(q[p], t);
            }
        }
    }

    const int b0 = wid * 4;
    #pragma unroll
    for (int p = 0; p < 4; ++p) {
        float r0 = fmaf(q[p].y, w4.z, q[p].x * w4.x);
        float r1 = fmaf(q[p].y, w4.w, q[p].x * w4.y);
        #pragma unroll
        for (int off = 32; off; off >>= 1) {
            r0 += __shfl_xor(r0, off, 64);
            r1 += __shfl_xor(r1, off, 64);
        }
        if (lane == 0) {
            float2 o; o.x = r0 + bias0; o.y = r1 + bias1;
            *(float2*)(out + (size_t)(b0 + p) * 2) = o;
        }
    }
}

extern "C" void kernel_launch(void* const* d_in, const int* in_sizes, int n_in,
                              void* d_out, int out_size, void* d_ws, size_t ws_size,
                              hipStream_t stream)
{
    const float* seq    = (const float*)d_in[0];
    const float* relpos = (const float*)d_in[1];
    const float* Wi     = (const float*)d_in[2];
    const float* bi     = (const float*)d_in[3];
    const float* Wj     = (const float*)d_in[4];
    const float* bj     = (const float*)d_in[5];
    const float* Wr     = (const float*)d_in[6];
    const float* br     = (const float*)d_in[7];
    const float* W1     = (const float*)d_in[8];
    const float* b1     = (const float*)d_in[9];
    const float* W2     = (const float*)d_in[10];
    const float* b2     = (const float*)d_in[11];
    float* out = (float*)d_out;
    float* ws  = (float*)d_ws;

    precomp_kernel<<<81, 128, 0, stream>>>(relpos, Wi, bi, Wj, bj, Wr, br, W1, b1, ws);

    // 1024 blocks x 4 waves; each wave owns 4 contiguous batches (4096*4 = 16384).
    outersum_main<<<1024, 256, 0, stream>>>(seq, ws, W2, b2, out);
}

// Round 8
// 142.274 us; speedup vs baseline: 1.3450x; 1.3450x over previous
//
#include <hip/hip_runtime.h>
#include <hip/hip_bf16.h>

// Problem constants
#define BB 16384
#define LL 9
#define DD 32
#define CR 128

typedef float v2 __attribute__((ext_vector_type(2)));

// --- VOP3P packed-fp32 ops (validated numerically in R7) ---
__device__ __forceinline__ v2 pk_fma_lo(v2 s, v2 a, v2 c) {
    v2 d;
    asm("v_pk_fma_f32 %0, %1, %2, %3 op_sel:[0,0,0] op_sel_hi:[0,1,1]"
        : "=v"(d) : "v"(s), "v"(a), "v"(c));
    return d;
}
__device__ __forceinline__ v2 pk_fma_hi(v2 s, v2 a, v2 c) {
    v2 d;
    asm("v_pk_fma_f32 %0, %1, %2, %3 op_sel:[1,0,0] op_sel_hi:[1,1,1]"
        : "=v"(d) : "v"(s), "v"(a), "v"(c));
    return d;
}
__device__ __forceinline__ v2 pk_add(v2 a, v2 b) {
    v2 d;
    asm("v_pk_add_f32 %0, %1, %2" : "=v"(d) : "v"(a), "v"(b));
    return d;
}

// async global->LDS, 16B per lane, dest = wave-uniform base + lane*16
__device__ __forceinline__ void gload_lds16(const float* g, float* l) {
    __builtin_amdgcn_global_load_lds(
        (const __attribute__((address_space(1))) void*)g,
        (__attribute__((address_space(3))) void*)l, 16, 0, 0);
}

#define VMW(N) asm volatile("s_waitcnt vmcnt(" #N ")" ::: "memory")

// ws float layout (LDS image, 10368 floats):
//   [0..8191]     AB: (d*64 + l)*4 + {0:A1[d][l],1:A1[d][l+64],2:A2[d][l],3:A2[d][l+64]}
//   [8192..10367] WK: 8192 + k*128 + l*2 + h  -> WK[k][l + 64h], k = i-j+8
__global__ void precomp_kernel(const float* __restrict__ relpos,
                               const float* __restrict__ Wi, const float* __restrict__ bi,
                               const float* __restrict__ Wj, const float* __restrict__ bj,
                               const float* __restrict__ Wr, const float* __restrict__ br,
                               const float* __restrict__ W1, const float* __restrict__ b1,
                               float* __restrict__ ws)
{
    const int tid = threadIdx.x;
    const int blk = blockIdx.x;           // 0..40
    if (blk < DD) {
        const int d = blk;
        const int c = tid & 127;
        const int which = tid >> 7;       // 0 = A1 (Wi), 1 = A2 (Wj)
        const float* W = which ? Wj : Wi;
        float s = 0.f;
        #pragma unroll
        for (int e = 0; e < DD; ++e) s = fmaf(W[d * DD + e], W1[e * CR + c], s);
        ws[(d * 64 + (c & 63)) * 4 + which * 2 + (c >> 6)] = s;
    } else {
        const int q = blk - DD;           // 0..8; k = 2q, 2q+1 (q=8: k=16 only)
        __shared__ float rv2[2][DD];
        const int nk = (q < 8) ? 2 : 1;
        if (tid < 64) {
            const int kk = tid >> 5;
            const int e = tid & 31;
            if (kk < nk) {
                const int k = q * 2 + kk;
                const int dk = k - 8;
                const int i = dk > 0 ? dk : 0;
                const int j = i - dk;
                float s = bi[e] + bj[e] + br[e];
                #pragma unroll
                for (int d = 0; d < DD; ++d)
                    s = fmaf(relpos[(i * LL + j) * DD + d], Wr[d * DD + e], s);
                rv2[kk][e] = s;
            }
        }
        __syncthreads();
        const int kk = tid >> 7;
        const int c = tid & 127;
        if (kk < nk) {
            const int k = q * 2 + kk;
            float s = b1[c];
            #pragma unroll
            for (int e = 0; e < DD; ++e) s = fmaf(rv2[kk][e], W1[e * CR + c], s);
            ws[8192 + k * 128 + (c & 63) * 2 + (c >> 6)] = s;
        }
    }
}

// One batch: U/V GEMV from LDS tables + uniform-broadcast seq reads, then
// diagonal outer sum with WK from LDS, W2 folded once, wave reduce, store.
__device__ __noinline__ void compute_batch(
    const float* AB, const float* WKL, const float* buf, int lane,
    float w2ax, float w2ay, float w2bx, float w2by,
    float bias0, float bias1, float* out, int b)
{
    v2 U[LL], V[LL];
    #pragma unroll
    for (int i = 0; i < LL; ++i) { U[i] = (v2)0.f; V[i] = (v2)0.f; }

    #pragma unroll
    for (int dc = 0; dc < 8; ++dc) {
        const float4 A0 = *(const float4*)&AB[((dc * 4 + 0) * 64 + lane) * 4];
        const float4 A1_ = *(const float4*)&AB[((dc * 4 + 1) * 64 + lane) * 4];
        const float4 A2_ = *(const float4*)&AB[((dc * 4 + 2) * 64 + lane) * 4];
        const float4 A3_ = *(const float4*)&AB[((dc * 4 + 3) * 64 + lane) * 4];
        v2 a1v0; a1v0.x = A0.x; a1v0.y = A0.y;
        v2 a2v0; a2v0.x = A0.z; a2v0.y = A0.w;
        v2 a1v1; a1v1.x = A1_.x; a1v1.y = A1_.y;
        v2 a2v1; a2v1.x = A1_.z; a2v1.y = A1_.w;
        v2 a1v2; a1v2.x = A2_.x; a1v2.y = A2_.y;
        v2 a2v2; a2v2.x = A2_.z; a2v2.y = A2_.w;
        v2 a1v3; a1v3.x = A3_.x; a1v3.y = A3_.y;
        v2 a2v3; a2v3.x = A3_.z; a2v3.y = A3_.w;
        #pragma unroll
        for (int i = 0; i < LL; ++i) {
            const float4 s = *(const float4*)&buf[i * DD + dc * 4];  // uniform bcast
            v2 s01; s01.x = s.x; s01.y = s.y;
            v2 s23; s23.x = s.z; s23.y = s.w;
            U[i] = pk_fma_lo(s01, a1v0, U[i]);
            U[i] = pk_fma_hi(s01, a1v1, U[i]);
            U[i] = pk_fma_lo(s23, a1v2, U[i]);
            U[i] = pk_fma_hi(s23, a1v3, U[i]);
            V[i] = pk_fma_lo(s01, a2v0, V[i]);
            V[i] = pk_fma_hi(s01, a2v1, V[i]);
            V[i] = pk_fma_lo(s23, a2v2, V[i]);
            V[i] = pk_fma_hi(s23, a2v3, V[i]);
        }
    }

    v2 qa = (v2)0.f, qb = (v2)0.f;
    #pragma unroll
    for (int k = 0; k < 17; ++k) {
        const v2 w = *(const v2*)&WKL[k * CR + lane * 2];
        const int dk = k - 8;
        const int i0 = dk > 0 ? dk : 0;
        const int cnt = LL - (dk > 0 ? dk : -dk);
        #pragma unroll
        for (int t = 0; t < cnt; ++t) {
            const int i = i0 + t, j = i - dk;
            v2 x = pk_add(U[i], V[j]);
            x = pk_add(x, w);
            x.x = fmaxf(x.x, 0.f);
            x.y = fmaxf(x.y, 0.f);
            if (t & 1) qb = pk_add(qb, x); else qa = pk_add(qa, x);
        }
    }
    const v2 q = pk_add(qa, qb);

    float r0 = fmaf(q.y, w2bx, q.x * w2ax);
    float r1 = fmaf(q.y, w2by, q.x * w2ay);
    #pragma unroll
    for (int off = 32; off; off >>= 1) {
        r0 += __shfl_xor(r0, off, 64);
        r1 += __shfl_xor(r1, off, 64);
    }
    if (lane == 0) {
        float2 o; o.x = r0 + bias0; o.y = r1 + bias1;
        *(float2*)(out + (size_t)b * 2) = o;
    }
}

__device__ __forceinline__ void stage_batch(const float* seq, int b, float* buf, int lane) {
    const float* g0 = seq + b * 288 + lane * 4;
    const float* g1 = g0 + 256;
    // last-batch guard: 2nd instr covers bytes past the batch; clamp OOB lanes
    if (b * 288 + 260 + lane * 4 > BB * 288) g1 = seq;
    gload_lds16(g0, buf);
    gload_lds16(g1, buf + 256);
}

__global__ __launch_bounds__(512, 4)
void outersum_main(const float* __restrict__ seq,
                   const float* __restrict__ ws,
                   const float* __restrict__ W2,
                   const float* __restrict__ b2,
                   float* __restrict__ out)
{
    __shared__ float lds[10368 + 8 * 1024];   // 41.5 KB tables + 8 waves * 2 * 2KB seq
    const int tid = threadIdx.x;

    // Stage table image (10368 floats = 2592 float4) cooperatively.
    {
        const float4* s4 = (const float4*)ws;
        float4* d4 = (float4*)lds;
        #pragma unroll
        for (int r = 0; r < 5; ++r) d4[tid + r * 512] = s4[tid + r * 512];
        if (tid < 32) d4[2560 + tid] = s4[2560 + tid];
    }
    __syncthreads();   // drains staging vmcnt -> counted waits below start clean

    const int lane = tid & 63;
    const int wv = tid >> 6;
    const float* AB  = lds;
    const float* WKL = lds + 8192;
    float* B0 = lds + 10368 + wv * 1024;
    float* B1 = B0 + 512;

    // Launder epilogue constants into VGPRs: nothing may re-load globals inside
    // the counted-vmcnt region.
    float w2ax = W2[2 * lane + 0],      w2ay = W2[2 * lane + 1];
    float w2bx = W2[2 * (lane + 64)],   w2by = W2[2 * (lane + 64) + 1];
    float bias0 = 81.f * b2[0], bias1 = 81.f * b2[1];
    asm volatile("" : "+v"(w2ax), "+v"(w2ay), "+v"(w2bx), "+v"(w2by),
                      "+v"(bias0), "+v"(bias1));

    const int b0 = (blockIdx.x * 8 + wv) * 4;

    // Software pipeline: stage ahead, counted vmcnt (stores accounted).
    stage_batch(seq, b0 + 0, B0, lane);
    stage_batch(seq, b0 + 1, B1, lane);
    VMW(2);
    compute_batch(AB, WKL, B0, lane, w2ax, w2ay, w2bx, w2by, bias0, bias1, out, b0 + 0);
    stage_batch(seq, b0 + 2, B0, lane);
    VMW(3);
    compute_batch(AB, WKL, B1, lane, w2ax, w2ay, w2bx, w2by, bias0, bias1, out, b0 + 1);
    stage_batch(seq, b0 + 3, B1, lane);
    VMW(3);
    compute_batch(AB, WKL, B0, lane, w2ax, w2ay, w2bx, w2by, bias0, bias1, out, b0 + 2);
    VMW(1);
    compute_batch(AB, WKL, B1, lane, w2ax, w2ay, w2bx, w2by, bias0, bias1, out, b0 + 3);
}

extern "C" void kernel_launch(void* const* d_in, const int* in_sizes, int n_in,
                              void* d_out, int out_size, void* d_ws, size_t ws_size,
                              hipStream_t stream)
{
    const float* seq    = (const float*)d_in[0];
    const float* relpos = (const float*)d_in[1];
    const float* Wi     = (const float*)d_in[2];
    const float* bi     = (const float*)d_in[3];
    const float* Wj     = (const float*)d_in[4];
    const float* bj     = (const float*)d_in[5];
    const float* Wr     = (const float*)d_in[6];
    const float* br     = (const float*)d_in[7];
    const float* W1     = (const float*)d_in[8];
    const float* b1     = (const float*)d_in[9];
    const float* W2     = (const float*)d_in[10];
    const float* b2     = (const float*)d_in[11];
    float* out = (float*)d_out;
    float* ws  = (float*)d_ws;

    precomp_kernel<<<41, 256, 0, stream>>>(relpos, Wi, bi, Wj, bj, Wr, br, W1, b1, ws);

    // 512 blocks x 8 waves x 4 batches = 16384. LDS 74240 B -> 2 blocks/CU,
    // launch_bounds(512,4) caps VGPR at 128 -> 16 waves/CU.
    outersum_main<<<512, 512, 0, stream>>>(seq, ws, W2, b2, out);
}

// Round 9
// 132.664 us; speedup vs baseline: 1.4425x; 1.0724x over previous
//
#include <hip/hip_runtime.h>
#include <hip/hip_bf16.h>

// Problem constants
#define BB 16384
#define LL 9
#define DD 32
#define CR 128

typedef float v2 __attribute__((ext_vector_type(2)));

// --- VOP3P packed-fp32 ops (validated numerically in R7/R8) ---
__device__ __forceinline__ v2 pk_fma_lo(v2 s, v2 a, v2 c) {
    v2 d;
    asm("v_pk_fma_f32 %0, %1, %2, %3 op_sel:[0,0,0] op_sel_hi:[0,1,1]"
        : "=v"(d) : "v"(s), "v"(a), "v"(c));
    return d;
}
__device__ __forceinline__ v2 pk_fma_hi(v2 s, v2 a, v2 c) {
    v2 d;
    asm("v_pk_fma_f32 %0, %1, %2, %3 op_sel:[1,0,0] op_sel_hi:[1,1,1]"
        : "=v"(d) : "v"(s), "v"(a), "v"(c));
    return d;
}
__device__ __forceinline__ v2 pk_add(v2 a, v2 b) {
    v2 d;
    asm("v_pk_add_f32 %0, %1, %2" : "=v"(d) : "v"(a), "v"(b));
    return d;
}

// async global->LDS, 16B per lane, dest = wave-uniform base + lane*16
__device__ __forceinline__ void gload_lds16(const float* g, float* l) {
    __builtin_amdgcn_global_load_lds(
        (const __attribute__((address_space(1))) void*)g,
        (__attribute__((address_space(3))) void*)l, 16, 0, 0);
}

#define VMW(N) asm volatile("s_waitcnt vmcnt(" #N ")" ::: "memory")

// ws float layout (LDS image, 10368 floats):
//   [0..8191]     AB: (d*64 + l)*4 + {0:A1[d][l],1:A1[d][l+64],2:A2[d][l],3:A2[d][l+64]}
//   [8192..10367] WK: 8192 + k*128 + l*2 + h  -> WK[k][l + 64h], k = i-j+8
__global__ void precomp_kernel(const float* __restrict__ relpos,
                               const float* __restrict__ Wi, const float* __restrict__ bi,
                               const float* __restrict__ Wj, const float* __restrict__ bj,
                               const float* __restrict__ Wr, const float* __restrict__ br,
                               const float* __restrict__ W1, const float* __restrict__ b1,
                               float* __restrict__ ws)
{
    const int tid = threadIdx.x;
    const int blk = blockIdx.x;           // 0..40
    if (blk < DD) {
        const int d = blk;
        const int c = tid & 127;
        const int which = tid >> 7;       // 0 = A1 (Wi), 1 = A2 (Wj)
        const float* W = which ? Wj : Wi;
        float s = 0.f;
        #pragma unroll
        for (int e = 0; e < DD; ++e) s = fmaf(W[d * DD + e], W1[e * CR + c], s);
        ws[(d * 64 + (c & 63)) * 4 + which * 2 + (c >> 6)] = s;
    } else {
        const int q = blk - DD;           // 0..8; k = 2q, 2q+1 (q=8: k=16 only)
        __shared__ float rv2[2][DD];
        const int nk = (q < 8) ? 2 : 1;
        if (tid < 64) {
            const int kk = tid >> 5;
            const int e = tid & 31;
            if (kk < nk) {
                const int k = q * 2 + kk;
                const int dk = k - 8;
                const int i = dk > 0 ? dk : 0;
                const int j = i - dk;
                float s = bi[e] + bj[e] + br[e];
                #pragma unroll
                for (int d = 0; d < DD; ++d)
                    s = fmaf(relpos[(i * LL + j) * DD + d], Wr[d * DD + e], s);
                rv2[kk][e] = s;
            }
        }
        __syncthreads();
        const int kk = tid >> 7;
        const int c = tid & 127;
        if (kk < nk) {
            const int k = q * 2 + kk;
            float s = b1[c];
            #pragma unroll
            for (int e = 0; e < DD; ++e) s = fmaf(rv2[kk][e], W1[e * CR + c], s);
            ws[8192 + k * 128 + (c & 63) * 2 + (c >> 6)] = s;
        }
    }
}

__device__ __forceinline__ void stage_batch(const float* seq, int b, float* buf, int lane) {
    const float* g0 = seq + b * 288 + lane * 4;
    const float* g1 = g0 + 256;
    // last-batch guard: 2nd instr covers bytes past the array; clamp OOB lanes
    if (b * 288 + 260 + lane * 4 > BB * 288) g1 = seq;
    gload_lds16(g0, buf);
    gload_lds16(g1, buf + 256);
}

__global__ __launch_bounds__(512, 4)
void outersum_main(const float* __restrict__ seq,
                   const float* __restrict__ ws,
                   const float* __restrict__ W2,
                   const float* __restrict__ b2,
                   float* __restrict__ out)
{
    __shared__ float lds[10368 + 8 * 1024];   // 41.5 KB tables + 8 waves * 2 * 2KB seq
    const int tid = threadIdx.x;

    // Stage table image (10368 floats = 2592 float4) cooperatively.
    {
        const float4* s4 = (const float4*)ws;
        float4* d4 = (float4*)lds;
        #pragma unroll
        for (int r = 0; r < 5; ++r) d4[tid + r * 512] = s4[tid + r * 512];
        if (tid < 32) d4[2560 + tid] = s4[2560 + tid];
    }

    const int lane = tid & 63;
    const int wv = tid >> 6;
    const float* AB  = lds;
    const float* WKL = lds + 8192;
    float* B0 = lds + 10368 + wv * 1024;
    float* B1 = B0 + 512;

    // Epilogue constants in VGPRs; launder BEFORE staging so their VMEM loads
    // are fully drained and can't perturb the counted-vmcnt region.
    float w2ax = W2[2 * lane + 0],      w2ay = W2[2 * lane + 1];
    float w2bx = W2[2 * (lane + 64)],   w2by = W2[2 * (lane + 64) + 1];
    float bias0 = 81.f * b2[0], bias1 = 81.f * b2[1];
    asm volatile("" : "+v"(w2ax), "+v"(w2ay), "+v"(w2bx), "+v"(w2by),
                      "+v"(bias0), "+v"(bias1));

    __syncthreads();   // table image ready; all prior VMEM drained -> clean vmcnt

    const int b0 = (blockIdx.x * 8 + wv) * 4;

    // Prologue: two batches in flight.
    stage_batch(seq, b0 + 0, B0, lane);
    stage_batch(seq, b0 + 1, B1, lane);

    float* cur = B0;
    float* nxt = B1;

    #pragma unroll 1
    for (int p = 0; p < 4; ++p) {
        VMW(2);   // current batch's 2 loads landed (2 newer ones may stay in flight)

        // Launder table pointers per-iteration: blocks LICM from hoisting the
        // 32xfloat4 AB tile out of the loop (the R7 register-blowup path).
        const float* ABl = AB;
        const float* WKLl = WKL;
        asm volatile("" : "+v"(ABl), "+v"(WKLl));

        // ---- GEMV: U/V from LDS tables, uniform-broadcast seq reads ----
        v2 U[LL], V[LL];
        #pragma unroll
        for (int i = 0; i < LL; ++i) { U[i] = (v2)0.f; V[i] = (v2)0.f; }

        #pragma unroll
        for (int dc = 0; dc < 8; ++dc) {
            const float4 A0 = *(const float4*)&ABl[((dc * 4 + 0) * 64 + lane) * 4];
            const float4 A1_ = *(const float4*)&ABl[((dc * 4 + 1) * 64 + lane) * 4];
            const float4 A2_ = *(const float4*)&ABl[((dc * 4 + 2) * 64 + lane) * 4];
            const float4 A3_ = *(const float4*)&ABl[((dc * 4 + 3) * 64 + lane) * 4];
            v2 a1v0; a1v0.x = A0.x; a1v0.y = A0.y;
            v2 a2v0; a2v0.x = A0.z; a2v0.y = A0.w;
            v2 a1v1; a1v1.x = A1_.x; a1v1.y = A1_.y;
            v2 a2v1; a2v1.x = A1_.z; a2v1.y = A1_.w;
            v2 a1v2; a1v2.x = A2_.x; a1v2.y = A2_.y;
            v2 a2v2; a2v2.x = A2_.z; a2v2.y = A2_.w;
            v2 a1v3; a1v3.x = A3_.x; a1v3.y = A3_.y;
            v2 a2v3; a2v3.x = A3_.z; a2v3.y = A3_.w;
            #pragma unroll
            for (int i = 0; i < LL; ++i) {
                const float4 s = *(const float4*)&cur[i * DD + dc * 4];  // uniform bcast
                v2 s01; s01.x = s.x; s01.y = s.y;
                v2 s23; s23.x = s.z; s23.y = s.w;
                U[i] = pk_fma_lo(s01, a1v0, U[i]);
                U[i] = pk_fma_hi(s01, a1v1, U[i]);
                U[i] = pk_fma_lo(s23, a1v2, U[i]);
                U[i] = pk_fma_hi(s23, a1v3, U[i]);
                V[i] = pk_fma_lo(s01, a2v0, V[i]);
                V[i] = pk_fma_hi(s01, a2v1, V[i]);
                V[i] = pk_fma_lo(s23, a2v2, V[i]);
                V[i] = pk_fma_hi(s23, a2v3, V[i]);
            }
        }

        // ---- outer sum over diagonals; WK from LDS once per diagonal ----
        v2 qa = (v2)0.f, qb = (v2)0.f;
        #pragma unroll
        for (int k = 0; k < 17; ++k) {
            const v2 w = *(const v2*)&WKLl[k * CR + lane * 2];
            const int dk = k - 8;
            const int i0 = dk > 0 ? dk : 0;
            const int cnt = LL - (dk > 0 ? dk : -dk);
            #pragma unroll
            for (int t = 0; t < cnt; ++t) {
                const int i = i0 + t, j = i - dk;
                v2 x = pk_add(U[i], V[j]);
                x = pk_add(x, w);
                x.x = fmaxf(x.x, 0.f);
                x.y = fmaxf(x.y, 0.f);
                if (t & 1) qb = pk_add(qb, x); else qa = pk_add(qa, x);
            }
        }
        const v2 q = pk_add(qa, qb);

        float r0 = fmaf(q.y, w2bx, q.x * w2ax);
        float r1 = fmaf(q.y, w2by, q.x * w2ay);
        #pragma unroll
        for (int off = 32; off; off >>= 1) {
            r0 += __shfl_xor(r0, off, 64);
            r1 += __shfl_xor(r1, off, 64);
        }
        if (lane == 0) {
            float2 o; o.x = r0 + bias0; o.y = r1 + bias1;
            *(float2*)(out + (size_t)(b0 + p) * 2) = o;
        }

        // Refill the just-consumed buffer with batch p+2 (dummy re-stage at the
        // tail keeps the vmcnt literal uniform; never read).
        int bs = b0 + p + 2;
        if (p >= 2) bs = b0;
        stage_batch(seq, bs, cur, lane);

        float* tswap = cur; cur = nxt; nxt = tswap;
    }
}

extern "C" void kernel_launch(void* const* d_in, const int* in_sizes, int n_in,
                              void* d_out, int out_size, void* d_ws, size_t ws_size,
                              hipStream_t stream)
{
    const float* seq    = (const float*)d_in[0];
    const float* relpos = (const float*)d_in[1];
    const float* Wi     = (const float*)d_in[2];
    const float* bi     = (const float*)d_in[3];
    const float* Wj     = (const float*)d_in[4];
    const float* bj     = (const float*)d_in[5];
    const float* Wr     = (const float*)d_in[6];
    const float* br     = (const float*)d_in[7];
    const float* W1     = (const float*)d_in[8];
    const float* b1     = (const float*)d_in[9];
    const float* W2     = (const float*)d_in[10];
    const float* b2     = (const float*)d_in[11];
    float* out = (float*)d_out;
    float* ws  = (float*)d_ws;

    precomp_kernel<<<41, 256, 0, stream>>>(relpos, Wi, bi, Wj, bj, Wr, br, W1, b1, ws);

    // 512 blocks x 8 waves x 4 batches = 16384. LDS 74240 B -> 2 blocks/CU,
    // launch_bounds(512,4) caps VGPR at 128 -> 16 waves/CU.
    outersum_main<<<512, 512, 0, stream>>>(seq, ws, W2, b2, out);
}